// Round 9
// baseline (320.624 us; speedup 1.0000x reference)
//
#include <hip/hip_runtime.h>
#include <hip/hip_bf16.h>

#define NTOK 49
#define NP 64
#define CDIM 256
#define NH 8
#define SCALE 0.17677669529663687f

using f32x4  = __attribute__((ext_vector_type(4))) float;
using bf16x8 = __attribute__((ext_vector_type(8))) short;

__device__ __forceinline__ unsigned f2bf_u(float f) {
  union { float f; unsigned u; } c; c.f = f;
  return (c.u + 0x7fffu + ((c.u >> 16) & 1u)) >> 16;   // RNE
}
__device__ __forceinline__ unsigned pk2(float a, float b) {
  return f2bf_u(a) | (f2bf_u(b) << 16);
}

// ---- LDS byte-offset helpers (all XOR swizzles preserve 16B alignment) ----
__device__ __forceinline__ int sx_b(int row, int col) {   // bf16 [64][256] x-stage
  return (row * 512 + col * 2) ^ ((row & 7) << 4);
}
// wave patch, row-major tile [64 rows][32 cols] bf16 (4KB): Q, K, O
__device__ __forceinline__ int rm_b(int row, int col) {
  return (row * 64 + col * 2) ^ ((row & 7) << 4);
}
// wave patch, V^T tile [32 feat][64 tok] bf16 (4KB)
__device__ __forceinline__ int vt_b(int feat, int tok) {
  return (feat * 128 + tok * 2) ^ ((feat & 7) << 4);
}
// wave patch, P tile [16 q][64 tok] bf16 (2KB)
__device__ __forceinline__ int p_b(int q, int tok) {
  return (q * 128 + tok * 2) ^ ((q & 7) << 4);
}

// ---------------- prep: bf16 weights (scale folded into Wq), TRANSPOSED bias table
// bias_att layout: [h][key_col][query_row] f32
__global__ void prep_kernel(const float* __restrict__ qkv_w, const float* __restrict__ qkv_b,
                            const float* __restrict__ proj_w,
                            const float* __restrict__ rpb, const int* __restrict__ rel,
                            short* __restrict__ wqkv, short* __restrict__ wp,
                            float* __restrict__ bias_s, float* __restrict__ bias_att) {
  int i = blockIdx.x * 256 + threadIdx.x;
  if (i < 768 * 256) {
    int j = i >> 8;
    float v = qkv_w[i] * (j < 256 ? SCALE : 1.0f);
    wqkv[i] = (short)f2bf_u(v);
    return;
  }
  i -= 768 * 256;
  if (i < 256 * 256) { wp[i] = (short)f2bf_u(proj_w[i]); return; }
  i -= 256 * 256;
  if (i < 768) { bias_s[i] = qkv_b[i] * (i < 256 ? SCALE : 1.0f); return; }
  i -= 768;
  if (i < NH * NP * NP) {
    int h = i >> 12, rem = i & 4095, c = rem >> 6, r = rem & 63;
    float v;
    if (c >= NTOK)      v = -1e30f;      // mask padded key columns
    else if (r >= NTOK) v = 0.0f;        // padded query rows: any finite value
    else                v = rpb[rel[r * NTOK + c] * NH + h];
    bias_att[i] = v;
  }
}

// 64x32(x256) per-wave GEMM over cols [col0, col0+32), k-outer, A from swizzled sx
__device__ __forceinline__ void gemm32c(const char* sxc, const short* __restrict__ wg,
                                        const float* __restrict__ bias,
                                        f32x4 acc[4][2], int col0, int lr, int lg) {
  const short* wr0 = wg + (col0 + lr) * CDIM + lg * 8;
  const short* wr1 = wg + (col0 + 16 + lr) * CDIM + lg * 8;
  const float bv0 = bias[col0 + lr];
  const float bv1 = bias[col0 + 16 + lr];
  #pragma unroll
  for (int rt = 0; rt < 4; ++rt) {
    #pragma unroll
    for (int r = 0; r < 4; ++r) { acc[rt][0][r] = bv0; acc[rt][1][r] = bv1; }
  }
  #pragma unroll
  for (int k = 0; k < 8; ++k) {
    const bf16x8 b0 = *(const bf16x8*)(wr0 + k * 32);
    const bf16x8 b1 = *(const bf16x8*)(wr1 + k * 32);
    #pragma unroll
    for (int rt = 0; rt < 4; ++rt) {
      const bf16x8 af = *(const bf16x8*)(sxc + sx_b(rt * 16 + lr, k * 32 + lg * 8));
      acc[rt][0] = __builtin_amdgcn_mfma_f32_16x16x32_bf16(af, b0, acc[rt][0], 0, 0, 0);
      acc[rt][1] = __builtin_amdgcn_mfma_f32_16x16x32_bf16(af, b1, acc[rt][1], 0, 0, 0);
    }
  }
}

// stage one batch of x (f32->bf16, rows >=49 zeroed) into sx; 512 threads
__device__ __forceinline__ void stage_x(char* sxc, const float* __restrict__ xg, int tid) {
  #pragma unroll
  for (int it = 0; it < 8; ++it) {
    const int i = tid + it * 512;
    const int row = i >> 6, c4 = i & 63;
    uint2 pkv = make_uint2(0u, 0u);
    if (row < NTOK) {
      const float4 v = *(const float4*)(xg + row * CDIM + c4 * 4);
      pkv.x = pk2(v.x, v.y); pkv.y = pk2(v.z, v.w);
    }
    *(uint2*)(sxc + sx_b(row, c4 * 4)) = pkv;
  }
}

// acc (64 rows x 32 cols, col-major-ish lanes) -> rm patch tile
__device__ __forceinline__ void acc_to_rm(char* pt, const f32x4 acc[4][2], int lr, int lg) {
  #pragma unroll
  for (int rt = 0; rt < 4; ++rt)
    #pragma unroll
    for (int ct = 0; ct < 2; ++ct)
      #pragma unroll
      for (int r = 0; r < 4; ++r)
        *(short*)(pt + rm_b(rt * 16 + lg * 4 + r, ct * 16 + lr)) =
            (short)f2bf_u(acc[rt][ct][r]);
}

// ================= FUSED v2: one batch/block, wave = head, 4 barriers =================
__global__ __launch_bounds__(512, 2)
void fused2(const float* __restrict__ x1, const float* __restrict__ x2,
            const short* __restrict__ wqkv, const float* __restrict__ bias_s,
            const short* __restrict__ wp, const float* __restrict__ proj_b,
            const float* __restrict__ bias_att, float* __restrict__ out) {
  extern __shared__ char lds[];
  char* sxc = lds;               // 32 KB x-stage (x1 then x2)
  char* pat = lds + 32768;       // 8 x 4 KB wave patches

  const int tid = threadIdx.x;
  const int w = tid >> 6, lane = tid & 63;
  const int lr = lane & 15, lg = lane >> 4;
  const int b = blockIdx.x;
  char* pt = pat + w * 4096;

  // ---- P1: stage x1 ----
  stage_x(sxc, x1 + (size_t)b * NTOK * CDIM, tid);
  __syncthreads();                                   // B1

  f32x4 acc[4][2];

  // ---- P2: Q gemm (head w) -> patch -> qa regs ----
  gemm32c(sxc, wqkv, bias_s, acc, w * 32, lr, lg);
  acc_to_rm(pt, acc, lr, lg);
  __syncthreads();                                   // B2 (x1 reads complete)
  bf16x8 qa[4];
  #pragma unroll
  for (int qt = 0; qt < 4; ++qt)
    qa[qt] = *(const bf16x8*)(pt + rm_b(qt * 16 + lr, lg * 8));

  // ---- P3: stage x2 over x1 ----
  stage_x(sxc, x2 + (size_t)b * NTOK * CDIM, tid);
  __syncthreads();                                   // B3

  // ---- P4: V gemm -> patch(vt) -> vb regs ----
  gemm32c(sxc, wqkv + 512 * CDIM, bias_s + 512, acc, w * 32, lr, lg);
  #pragma unroll
  for (int rt = 0; rt < 4; ++rt)
    #pragma unroll
    for (int ct = 0; ct < 2; ++ct) {
      uint2 pkv = make_uint2(pk2(acc[rt][ct][0], acc[rt][ct][1]),
                             pk2(acc[rt][ct][2], acc[rt][ct][3]));
      *(uint2*)(pt + vt_b(ct * 16 + lr, rt * 16 + lg * 4)) = pkv;
    }
  bf16x8 vb[2][2];
  #pragma unroll
  for (int kk = 0; kk < 2; ++kk)
    #pragma unroll
    for (int jt = 0; jt < 2; ++jt)
      vb[kk][jt] = *(const bf16x8*)(pt + vt_b(jt * 16 + lr, kk * 32 + lg * 8));

  // ---- P5: K gemm -> patch(rm) -> kb regs ----
  gemm32c(sxc, wqkv + 256 * CDIM, bias_s + 256, acc, w * 32, lr, lg);
  acc_to_rm(pt, acc, lr, lg);
  bf16x8 kb[4];
  #pragma unroll
  for (int ct = 0; ct < 4; ++ct)
    kb[ct] = *(const bf16x8*)(pt + rm_b(ct * 16 + lr, lg * 8));

  // ---- P6: attention head w, all 64 q-rows (wave-local, no barriers) ----
  const float* bht = bias_att + w * NP * NP;   // [key][query]
  f32x4 oacc[4][2];
  #pragma unroll
  for (int qt = 0; qt < 4; ++qt)
    #pragma unroll
    for (int jt = 0; jt < 2; ++jt) {
      oacc[qt][jt][0] = 0; oacc[qt][jt][1] = 0; oacc[qt][jt][2] = 0; oacc[qt][jt][3] = 0;
    }

  #pragma unroll 1
  for (int qt = 0; qt < 4; ++qt) {
    f32x4 s[4];
    #pragma unroll
    for (int ct = 0; ct < 4; ++ct) {
      const float4 sbv = *(const float4*)(bht + (ct * 16 + lr) * NP + qt * 16 + lg * 4);
      f32x4 sb; sb[0] = sbv.x; sb[1] = sbv.y; sb[2] = sbv.z; sb[3] = sbv.w;
      s[ct] = __builtin_amdgcn_mfma_f32_16x16x32_bf16(qa[qt], kb[ct], sb, 0, 0, 0);
    }
    float mx[4], si[4];
    #pragma unroll
    for (int r = 0; r < 4; ++r) {
      float m = fmaxf(fmaxf(s[0][r], s[1][r]), fmaxf(s[2][r], s[3][r]));
      m = fmaxf(m, __shfl_xor(m, 1, 64));
      m = fmaxf(m, __shfl_xor(m, 2, 64));
      m = fmaxf(m, __shfl_xor(m, 4, 64));
      m = fmaxf(m, __shfl_xor(m, 8, 64));
      mx[r] = m;
    }
    #pragma unroll
    for (int ct = 0; ct < 4; ++ct)
      #pragma unroll
      for (int r = 0; r < 4; ++r)
        s[ct][r] = __expf(s[ct][r] - mx[r]);
    #pragma unroll
    for (int r = 0; r < 4; ++r) {
      float t = s[0][r] + s[1][r] + s[2][r] + s[3][r];
      t += __shfl_xor(t, 1, 64);
      t += __shfl_xor(t, 2, 64);
      t += __shfl_xor(t, 4, 64);
      t += __shfl_xor(t, 8, 64);
      si[r] = __builtin_amdgcn_rcpf(t);
    }
    // P -> patch (2KB region; Q/K parts of patch are dead, kb/vb/qa live in regs)
    #pragma unroll
    for (int ct = 0; ct < 4; ++ct)
      #pragma unroll
      for (int r = 0; r < 4; ++r)
        *(short*)(pt + p_b(lg * 4 + r, ct * 16 + lr)) =
            (short)f2bf_u(s[ct][r] * si[r]);
    #pragma unroll
    for (int kk = 0; kk < 2; ++kk) {
      const bf16x8 pa = *(const bf16x8*)(pt + p_b(lr, kk * 32 + lg * 8));
      #pragma unroll
      for (int jt = 0; jt < 2; ++jt)
        oacc[qt][jt] = __builtin_amdgcn_mfma_f32_16x16x32_bf16(pa, vb[kk][jt], oacc[qt][jt], 0, 0, 0);
    }
  }

  // ---- P7: O tile -> patch (rm), barrier, proj from all patches ----
  #pragma unroll
  for (int qt = 0; qt < 4; ++qt)
    #pragma unroll
    for (int jt = 0; jt < 2; ++jt)
      #pragma unroll
      for (int r = 0; r < 4; ++r)
        *(short*)(pt + rm_b(qt * 16 + lg * 4 + r, jt * 16 + lr)) =
            (short)f2bf_u(oacc[qt][jt][r]);
  __syncthreads();                                   // B4

  // proj: wave w -> output cols [32w, 32w+32); A-tiles = the 8 patches
  {
    const short* wr0 = wp + (w * 32 + lr) * CDIM + lg * 8;
    const short* wr1 = wp + (w * 32 + 16 + lr) * CDIM + lg * 8;
    const float bv0 = proj_b[w * 32 + lr];
    const float bv1 = proj_b[w * 32 + 16 + lr];
    #pragma unroll
    for (int rt = 0; rt < 4; ++rt) {
      #pragma unroll
      for (int r = 0; r < 4; ++r) { acc[rt][0][r] = bv0; acc[rt][1][r] = bv1; }
    }
    #pragma unroll
    for (int k = 0; k < 8; ++k) {
      const bf16x8 b0 = *(const bf16x8*)(wr0 + k * 32);
      const bf16x8 b1 = *(const bf16x8*)(wr1 + k * 32);
      #pragma unroll
      for (int rt = 0; rt < 4; ++rt) {
        const bf16x8 af = *(const bf16x8*)(pat + k * 4096 + rm_b(rt * 16 + lr, lg * 8));
        acc[rt][0] = __builtin_amdgcn_mfma_f32_16x16x32_bf16(af, b0, acc[rt][0], 0, 0, 0);
        acc[rt][1] = __builtin_amdgcn_mfma_f32_16x16x32_bf16(af, b1, acc[rt][1], 0, 0, 0);
      }
    }
    float* og = out + (size_t)b * NTOK * CDIM;
    #pragma unroll
    for (int rt = 0; rt < 4; ++rt)
      #pragma unroll
      for (int r = 0; r < 4; ++r) {
        const int row = rt * 16 + lg * 4 + r;
        if (row < NTOK) {
          #pragma unroll
          for (int ct = 0; ct < 2; ++ct)
            og[row * CDIM + w * 32 + ct * 16 + lr] = acc[rt][ct][r];
        }
      }
  }
}

extern "C" void kernel_launch(void* const* d_in, const int* in_sizes, int n_in,
                              void* d_out, int out_size, void* d_ws, size_t ws_size,
                              hipStream_t stream) {
  const float* x1     = (const float*)d_in[0];
  const float* x2     = (const float*)d_in[1];
  const float* qkv_w  = (const float*)d_in[2];
  const float* qkv_b  = (const float*)d_in[3];
  const float* proj_w = (const float*)d_in[4];
  const float* proj_b = (const float*)d_in[5];
  const float* rpb    = (const float*)d_in[6];
  const int*   rel    = (const int*)d_in[7];

  char* ws = (char*)d_ws;
  short* wqkv     = (short*)ws;                         // 393216 B
  short* wp       = (short*)(ws + 393216);              // 131072 B
  float* bias_s   = (float*)(ws + 524288);              // 3072 B
  float* bias_att = (float*)(ws + 527360);              // 131072 B (transposed [h][key][query])

  const int prep_total = 768 * 256 + 256 * 256 + 768 + NH * NP * NP;
  prep_kernel<<<(prep_total + 255) / 256, 256, 0, stream>>>(
      qkv_w, qkv_b, proj_w, rpb, rel, wqkv, wp, bias_s, bias_att);

  const int Bn = in_sizes[0] / (NTOK * CDIM);
  const size_t shmem = 32768 + 8 * 4096;                // 65536
  (void)hipFuncSetAttribute((const void*)fused2,
                            hipFuncAttributeMaxDynamicSharedMemorySize, (int)shmem);
  fused2<<<Bn, 512, shmem, stream>>>(x1, x2, wqkv, bias_s, wp, proj_b, bias_att,
                                     (float*)d_out);
}